// Round 2
// baseline (307.564 us; speedup 1.0000x reference)
//
#include <hip/hip_runtime.h>

// PEG_Shift: depthwise 3x3 conv (stride 1, pad 1, groups=C), power-of-two weights,
// 16-bit fixed-point activations/bias. x: (32,384,56,56) f32.
//
// v3: zero-LDS register streaming. Each thread owns a 4-wide x 28-row column strip,
// walks down with a 3-row register window; horizontal halo = 2 scalar global loads
// (L1 hits from adjacent lanes). No __syncthreads, no LDS, no bank conflicts.
// 1344 blocks of 256 -> all co-resident (<=2048 slots), zero tail.
// Weight pow2-quant + bias quant hoisted to a tiny pre-kernel into d_ws.

#define DW_C     384
#define DW_H     56
#define DW_W     56
#define DW_HW    3136
#define SEG_ROWS 28
#define NW4      14

__device__ __forceinline__ float qfix(float v) {
    // floor(v * 2^16) * 2^-16, clip [-2^15, 2^15-1] — exact in fp32
    v = floorf(v * 65536.0f) * (1.0f / 65536.0f);
    return fminf(fmaxf(v, -32768.0f), 32767.0f);   // compiler emits v_med3_f32
}

struct Row { float l, a, b, c, d, r; };

// ---- pre-kernel: quantize 3456 weights (power of two) + 384 biases into d_ws ----
__global__ __launch_bounds__(256) void quant_wb(
    const float* __restrict__ wgt, const float* __restrict__ bias,
    float* __restrict__ wq, float* __restrict__ bq)
{
    int i = blockIdx.x * 256 + threadIdx.x;
    if (i < DW_C * 9) {
        float wv = wgt[i];
        float aw = fabsf(wv);
        float cw = fminf(fmaxf(aw, 6.103515625e-05f /*2^-14*/), 1.0f);
        float q  = exp2f(rintf(log2f(cw)));        // rint = round-half-even (jnp.round)
        wq[i] = (wv > 0.0f) ? q : ((wv < 0.0f) ? -q : 0.0f);
    }
    if (i < DW_C) bq[i] = qfix(bias[i]);
}

template<bool PRE>
__global__ __launch_bounds__(256, 6) void peg_shift_stream(
    const float* __restrict__ x, const float* __restrict__ wgt,
    const float* __restrict__ bias, float* __restrict__ out,
    const float* __restrict__ wsq, const float* __restrict__ wsb)
{
    const int task = blockIdx.x * 256 + threadIdx.x;
    // task -> (plane, seg, w4); seg inner so both halves of a plane are in the
    // same block (vertical-halo rows 27/28 hit L1/L2).
    const int plane = task / 28;
    const int t28   = task - plane * 28;
    const int seg   = t28 / NW4;
    const int w4    = t28 - seg * NW4;
    const int c     = plane % DW_C;
    const int r0    = seg * SEG_ROWS;

    const bool hl = (w4 > 0);
    const bool hr = (w4 < NW4 - 1);

    // ---- per-channel quantized weights + bias ----
    float ww[9];
    float bqv;
    if (PRE) {
        const float* wp = wsq + c * 9;
#pragma unroll
        for (int t = 0; t < 9; ++t) ww[t] = wp[t];
        bqv = wsb[c];
    } else {
        const float* wp = wgt + c * 9;
#pragma unroll
        for (int t = 0; t < 9; ++t) {
            float wv = wp[t];
            float aw = fabsf(wv);
            float cw = fminf(fmaxf(aw, 6.103515625e-05f), 1.0f);
            float q  = exp2f(rintf(log2f(cw)));
            ww[t] = (wv > 0.0f) ? q : ((wv < 0.0f) ? -q : 0.0f);
        }
        bqv = qfix(bias[c]);
    }

    const float* xb = x + (size_t)plane * DW_HW + w4 * 4;

    auto loadq = [&](int rr) -> Row {
        Row q;
        if (rr >= 0 && rr < DW_H) {
            const float* p = xb + rr * DW_W;
            float4 m = *(const float4*)p;          // aligned 16B
            float lv = hl ? p[-1] : 0.0f;          // L1 hit (neighbor lane's line)
            float rv = hr ? p[4]  : 0.0f;
            q.l = qfix(lv); q.a = qfix(m.x); q.b = qfix(m.y);
            q.c = qfix(m.z); q.d = qfix(m.w); q.r = qfix(rv);
        } else {
            q.l = q.a = q.b = q.c = q.d = q.r = 0.0f;   // zero padding row
        }
        return q;
    };

    // 3-row register window
    Row A = loadq(r0 - 1);    // seg0: row -1 -> zeros
    Row B = loadq(r0);
    Row C = loadq(r0 + 1);

    float* ob = out + (size_t)plane * DW_HW + r0 * DW_W + w4 * 4;

#pragma unroll 4
    for (int i = 0; i < SEG_ROWS; ++i) {
        // ---- prefetch row r+2 (raw) — lands under this row's 36 FMAs ----
        const int rr = r0 + i + 2;
        float4 pm; pm.x = pm.y = pm.z = pm.w = 0.0f;
        float pl = 0.0f, pr = 0.0f;
        if (rr < DW_H) {                           // only false in seg1's last 2 iters
            const float* p = xb + rr * DW_W;
            pm = *(const float4*)p;
            if (hl) pl = p[-1];
            if (hr) pr = p[4];
        }

        // ---- compute output row r0+i from window A,B,C ----
        float o0 = bqv, o1 = bqv, o2 = bqv, o3 = bqv;
        o0 = fmaf(A.l, ww[0], fmaf(A.a, ww[1], fmaf(A.b, ww[2], o0)));
        o1 = fmaf(A.a, ww[0], fmaf(A.b, ww[1], fmaf(A.c, ww[2], o1)));
        o2 = fmaf(A.b, ww[0], fmaf(A.c, ww[1], fmaf(A.d, ww[2], o2)));
        o3 = fmaf(A.c, ww[0], fmaf(A.d, ww[1], fmaf(A.r, ww[2], o3)));
        o0 = fmaf(B.l, ww[3], fmaf(B.a, ww[4], fmaf(B.b, ww[5], o0)));
        o1 = fmaf(B.a, ww[3], fmaf(B.b, ww[4], fmaf(B.c, ww[5], o1)));
        o2 = fmaf(B.b, ww[3], fmaf(B.c, ww[4], fmaf(B.d, ww[5], o2)));
        o3 = fmaf(B.c, ww[3], fmaf(B.d, ww[4], fmaf(B.r, ww[5], o3)));
        o0 = fmaf(C.l, ww[6], fmaf(C.a, ww[7], fmaf(C.b, ww[8], o0)));
        o1 = fmaf(C.a, ww[6], fmaf(C.b, ww[7], fmaf(C.c, ww[8], o1)));
        o2 = fmaf(C.b, ww[6], fmaf(C.c, ww[7], fmaf(C.d, ww[8], o2)));
        o3 = fmaf(C.c, ww[6], fmaf(C.d, ww[7], fmaf(C.r, ww[8], o3)));

        float4 ov; ov.x = o0; ov.y = o1; ov.z = o2; ov.w = o3;
        *(float4*)ob = ov;
        ob += DW_W;

        // ---- rotate window; quantize the prefetched row ----
        A = B; B = C;
        C.l = qfix(pl);   C.a = qfix(pm.x); C.b = qfix(pm.y);
        C.c = qfix(pm.z); C.d = qfix(pm.w); C.r = qfix(pr);
    }
}

extern "C" void kernel_launch(void* const* d_in, const int* in_sizes, int n_in,
                              void* d_out, int out_size, void* d_ws, size_t ws_size,
                              hipStream_t stream) {
    const float* x = (const float*)d_in[0];
    const float* w = (const float*)d_in[1];
    const float* b = (const float*)d_in[2];
    float* out = (float*)d_out;

    int planes  = in_sizes[0] / DW_HW;          // 32*384 = 12288
    int tasks   = planes * 28;                  // 344064
    int nblocks = (tasks + 255) / 256;          // 1344 -> all co-resident

    size_t need = (size_t)(DW_C * 9 + DW_C) * sizeof(float);
    if (d_ws && ws_size >= need) {
        float* wq = (float*)d_ws;
        float* bq = wq + DW_C * 9;
        quant_wb<<<(DW_C * 9 + 255) / 256, 256, 0, stream>>>(w, b, wq, bq);
        peg_shift_stream<true><<<nblocks, 256, 0, stream>>>(x, w, b, out, wq, bq);
    } else {
        peg_shift_stream<false><<<nblocks, 256, 0, stream>>>(x, w, b, out, nullptr, nullptr);
    }
}